// Round 6
// baseline (37.107 us; speedup 1.0000x reference)
//
#include <hip/hip_runtime.h>

// Masked scatter-add: out[index[i]] += rate[i] where starttime[i] <= t < endtime[i].
//
// R1: direct global atomics -> 250-way memory-side contention, 113 us.
// R2: LDS hist + partials + parallel reduce: 45 us.
// R3: plain-store reduce (8 workgroups) latency-bound at 118 us.
// R4: parallel reduce restored -> 36.5 us. Hist occupancy 18%, HBM 19%.
// R5: 1024-thr blocks -> occupancy 72%, ZERO speedup (35.4 us). TLP is not
//     the constraint; the 2-dependent-phase loop limits per-wave MLP to ~2-4
//     loads in flight.
// R6: batch-of-4 chunk processing: 8 s/e float4 loads issued back-to-back
//     (one wait), then 4 conditional idx/rate loads (one wait), then LDS
//     atomics. ~3x the bytes in flight per wave, 2 waits per 64 elements.

#define MAX_BINS 2048   // problem SIZE = 2000; static LDS must be compile-time
#define HIST_BLOCK 512

__global__ void __launch_bounds__(HIST_BLOCK, 4)   // cap VGPR at 128 -> 2 blocks/CU
hist_partial_kernel(const int* __restrict__ index,
                    const float* __restrict__ rate,
                    const float* __restrict__ starttime,
                    const float* __restrict__ endtime,
                    const float* __restrict__ t_ptr,
                    float* __restrict__ ws,   // [gridDim.x][size] partials
                    int n, int size)
{
    __shared__ float hist[MAX_BINS];
    for (int j = threadIdx.x; j < size; j += blockDim.x) hist[j] = 0.0f;
    __syncthreads();

    const float t = t_ptr[0];
    const int tid      = blockIdx.x * blockDim.x + threadIdx.x;
    const int nthreads = gridDim.x * blockDim.x;
    const int nvec     = n >> 2;

    const int4*   idx4v = reinterpret_cast<const int4*>(index);
    const float4* rat4v = reinterpret_cast<const float4*>(rate);
    const float4* st4v  = reinterpret_cast<const float4*>(starttime);
    const float4* en4v  = reinterpret_cast<const float4*>(endtime);

    int i = tid;

    // Main: 4 chunk-points per iteration. All 8 s/e loads issue before any
    // use (single vmcnt drain), then all conditional idx/rate loads issue
    // back-to-back (second drain), then predicated LDS atomics.
    for (; i + 3 * nthreads < nvec; i += 4 * nthreads) {
        const int i0 = i;
        const int i1 = i + nthreads;
        const int i2 = i + 2 * nthreads;
        const int i3 = i + 3 * nthreads;

        const float4 s0 = st4v[i0]; const float4 e0 = en4v[i0];
        const float4 s1 = st4v[i1]; const float4 e1 = en4v[i1];
        const float4 s2 = st4v[i2]; const float4 e2 = en4v[i2];
        const float4 s3 = st4v[i3]; const float4 e3 = en4v[i3];

        const bool a00 = (s0.x <= t) & (t < e0.x);
        const bool a01 = (s0.y <= t) & (t < e0.y);
        const bool a02 = (s0.z <= t) & (t < e0.z);
        const bool a03 = (s0.w <= t) & (t < e0.w);
        const bool a10 = (s1.x <= t) & (t < e1.x);
        const bool a11 = (s1.y <= t) & (t < e1.y);
        const bool a12 = (s1.z <= t) & (t < e1.z);
        const bool a13 = (s1.w <= t) & (t < e1.w);
        const bool a20 = (s2.x <= t) & (t < e2.x);
        const bool a21 = (s2.y <= t) & (t < e2.y);
        const bool a22 = (s2.z <= t) & (t < e2.z);
        const bool a23 = (s2.w <= t) & (t < e2.w);
        const bool a30 = (s3.x <= t) & (t < e3.x);
        const bool a31 = (s3.y <= t) & (t < e3.y);
        const bool a32 = (s3.z <= t) & (t < e3.z);
        const bool a33 = (s3.w <= t) & (t < e3.w);

        const bool any0 = a00 | a01 | a02 | a03;
        const bool any1 = a10 | a11 | a12 | a13;
        const bool any2 = a20 | a21 | a22 | a23;
        const bool any3 = a30 | a31 | a32 | a33;

        int4 I0, I1, I2, I3; float4 R0, R1, R2, R3;
        // ~18.5% of chunks contain an active event: fetch idx/rate lines only
        // for those. Branch bodies are load-only -> no waits between them.
        if (any0) { I0 = idx4v[i0]; R0 = rat4v[i0]; }
        if (any1) { I1 = idx4v[i1]; R1 = rat4v[i1]; }
        if (any2) { I2 = idx4v[i2]; R2 = rat4v[i2]; }
        if (any3) { I3 = idx4v[i3]; R3 = rat4v[i3]; }

        if (any0) {
            if (a00) atomicAdd(&hist[I0.x], R0.x);   // ds_add_f32, uncontended
            if (a01) atomicAdd(&hist[I0.y], R0.y);
            if (a02) atomicAdd(&hist[I0.z], R0.z);
            if (a03) atomicAdd(&hist[I0.w], R0.w);
        }
        if (any1) {
            if (a10) atomicAdd(&hist[I1.x], R1.x);
            if (a11) atomicAdd(&hist[I1.y], R1.y);
            if (a12) atomicAdd(&hist[I1.z], R1.z);
            if (a13) atomicAdd(&hist[I1.w], R1.w);
        }
        if (any2) {
            if (a20) atomicAdd(&hist[I2.x], R2.x);
            if (a21) atomicAdd(&hist[I2.y], R2.y);
            if (a22) atomicAdd(&hist[I2.z], R2.z);
            if (a23) atomicAdd(&hist[I2.w], R2.w);
        }
        if (any3) {
            if (a30) atomicAdd(&hist[I3.x], R3.x);
            if (a31) atomicAdd(&hist[I3.y], R3.y);
            if (a32) atomicAdd(&hist[I3.z], R3.z);
            if (a33) atomicAdd(&hist[I3.w], R3.w);
        }
    }

    // Remainder chunk-points (fewer than 4 strides left).
    for (; i < nvec; i += nthreads) {
        const float4 s4 = st4v[i];
        const float4 e4 = en4v[i];
        const bool a0 = (s4.x <= t) & (t < e4.x);
        const bool a1 = (s4.y <= t) & (t < e4.y);
        const bool a2 = (s4.z <= t) & (t < e4.z);
        const bool a3 = (s4.w <= t) & (t < e4.w);
        if (a0 | a1 | a2 | a3) {
            const int4   i4 = idx4v[i];
            const float4 r4 = rat4v[i];
            if (a0) atomicAdd(&hist[i4.x], r4.x);
            if (a1) atomicAdd(&hist[i4.y], r4.y);
            if (a2) atomicAdd(&hist[i4.z], r4.z);
            if (a3) atomicAdd(&hist[i4.w], r4.w);
        }
    }

    // Element tail (N % 4) — N=10M divisible by 4, but stay generic.
    for (int k = (nvec << 2) + tid; k < n; k += nthreads) {
        if (starttime[k] <= t && t < endtime[k]) atomicAdd(&hist[index[k]], rate[k]);
    }

    __syncthreads();

    // Coalesced, vectorized flush of this block's private partial row.
    float* part = ws + (size_t)blockIdx.x * size;
    const int nq = size >> 2;
    float4* part4 = reinterpret_cast<float4*>(part);
    const float4* hist4 = reinterpret_cast<const float4*>(hist);
    for (int j = threadIdx.x; j < nq; j += blockDim.x) part4[j] = hist4[j];
    for (int j = (nq << 2) + threadIdx.x; j < size; j += blockDim.x) part[j] = hist[j];
}

// Parallel over partials: block (x=j-tile, y=b-chunk). Each thread sums its
// chunk (coalesced: lanes read consecutive j at fixed b) then ONE atomicAdd.
// gridDim.y-way contention per bin -- negligible.
__global__ void __launch_bounds__(256)
reduce_partials_kernel(const float* __restrict__ ws,
                       float* __restrict__ out,
                       int npart, int size)
{
    const int j = blockIdx.x * blockDim.x + threadIdx.x;
    if (j >= size) return;

    const int chunk  = npart / gridDim.y;
    const int bstart = blockIdx.y * chunk;
    const int bend   = (blockIdx.y == gridDim.y - 1) ? npart : bstart + chunk;

    float sum = 0.0f;
    int b = bstart;
    #pragma unroll 8
    for (; b + 8 <= bend; b += 8) {
        sum += ws[(size_t)(b + 0) * size + j];
        sum += ws[(size_t)(b + 1) * size + j];
        sum += ws[(size_t)(b + 2) * size + j];
        sum += ws[(size_t)(b + 3) * size + j];
        sum += ws[(size_t)(b + 4) * size + j];
        sum += ws[(size_t)(b + 5) * size + j];
        sum += ws[(size_t)(b + 6) * size + j];
        sum += ws[(size_t)(b + 7) * size + j];
    }
    for (; b < bend; ++b) sum += ws[(size_t)b * size + j];

    atomicAdd(&out[j], sum);
}

// Fallback (ws too small / size too large): direct predicated global atomics.
__global__ void __launch_bounds__(256)
direct_atomic_kernel(const int* __restrict__ index,
                     const float* __restrict__ rate,
                     const float* __restrict__ starttime,
                     const float* __restrict__ endtime,
                     const float* __restrict__ t_ptr,
                     float* __restrict__ out, int n)
{
    const float t = t_ptr[0];
    const int tid      = blockIdx.x * blockDim.x + threadIdx.x;
    const int nthreads = gridDim.x * blockDim.x;
    for (int i = tid; i < n; i += nthreads) {
        if (starttime[i] <= t && t < endtime[i]) atomicAdd(&out[index[i]], rate[i]);
    }
}

extern "C" void kernel_launch(void* const* d_in, const int* in_sizes, int n_in,
                              void* d_out, int out_size, void* d_ws, size_t ws_size,
                              hipStream_t stream)
{
    const int*   index     = (const int*)  d_in[0];
    const float* rate      = (const float*)d_in[1];
    const float* starttime = (const float*)d_in[2];
    const float* endtime   = (const float*)d_in[3];
    const float* t_ptr     = (const float*)d_in[4];

    float* out = (float*)d_out;
    float* ws  = (float*)d_ws;
    const int n    = in_sizes[0];
    const int size = out_size;

    // Atomic reduce accumulates into d_out -> zero it every call (replays are
    // not re-poisoned by the harness).
    hipMemsetAsync(out, 0, (size_t)size * sizeof(float), stream);

    // npart=512 partial rows (4 MB traffic); 512 threads/block, 2 blocks/CU.
    int npart = (int)(ws_size / ((size_t)size * sizeof(float)));
    if (npart > 512) npart = 512;

    if (size <= MAX_BINS && npart >= 64) {
        hist_partial_kernel<<<npart, HIST_BLOCK, 0, stream>>>(
            index, rate, starttime, endtime, t_ptr, ws, n, size);

        dim3 g2((size + 255) / 256, 16);   // 128 blocks, 32 loads/thread
        reduce_partials_kernel<<<g2, 256, 0, stream>>>(ws, out, npart, size);
    } else {
        int grid = (n + 255) / 256;
        if (grid > 2048) grid = 2048;
        direct_atomic_kernel<<<grid, 256, 0, stream>>>(
            index, rate, starttime, endtime, t_ptr, out, n);
    }
}